// Round 1
// baseline (94.438 us; speedup 1.0000x reference)
//
#include <hip/hip_runtime.h>
#include <math.h>

#define CCH  32
#define NPIX 4096   // 64*64
#define BB   2

// ---------------------------------------------------------------------------
// K1: G[b,i,j] = sum_n Xhat[b,i,n] * X[b,j,n]     (B x 32 x 32 Gram matrices)
// grid: B*32*32 = 2048 blocks, 256 threads; each block = one 4096-length dot.
// ---------------------------------------------------------------------------
__global__ __launch_bounds__(256) void k_gram(const float* __restrict__ X,
                                              const float* __restrict__ Xh,
                                              float* __restrict__ G) {
    int blk = blockIdx.x;           // b*1024 + i*32 + j
    int b = blk >> 10;
    int i = (blk >> 5) & 31;
    int j = blk & 31;
    const float4* xh = (const float4*)(Xh + (size_t)(b*CCH + i) * NPIX);
    const float4* xv = (const float4*)(X  + (size_t)(b*CCH + j) * NPIX);
    int t = threadIdx.x;
    float s = 0.f;
    #pragma unroll
    for (int k = 0; k < 4; ++k) {
        float4 a = xh[t + k*256];
        float4 c = xv[t + k*256];
        s += a.x*c.x + a.y*c.y + a.z*c.z + a.w*c.w;
    }
    #pragma unroll
    for (int off = 32; off > 0; off >>= 1)
        s += __shfl_down(s, off, 64);
    __shared__ float red[4];
    int lane = t & 63, wid = t >> 6;
    if (lane == 0) red[wid] = s;
    __syncthreads();
    if (t == 0) G[blk] = red[0] + red[1] + red[2] + red[3];
}

// ---------------------------------------------------------------------------
// K2: wEff[b,o,i,k] = (1/sqrt(C)) * sum_c w[o,c,k] * G[b,i,c]
// grid: B*32 = 64 blocks (b,o), 256 threads loop over 288 (i,k) outputs.
// ---------------------------------------------------------------------------
__global__ __launch_bounds__(256) void k_weff(const float* __restrict__ wConv, // (O,C,3,3)
                                              const float* __restrict__ G,    // (B,C,C)
                                              float* __restrict__ wEff) {     // (B,O,C,9)
    int b = blockIdx.x >> 5;
    int o = blockIdx.x & 31;
    const float rs = 0.17677669529663687f; // 1/sqrt(32)
    for (int r = threadIdx.x; r < CCH*9; r += 256) {
        int i = r / 9, k = r - 9*(r/9);
        float s = 0.f;
        #pragma unroll 8
        for (int c = 0; c < CCH; ++c)
            s += wConv[(o*CCH + c)*9 + k] * G[(b*CCH + i)*CCH + c];
        wEff[((b*CCH + o)*CCH + i)*9 + k] = s * rs;
    }
}

// ---------------------------------------------------------------------------
// K3: conv_out[b,o,y,x] = bias[o] + sum_i sum_k wEff[b,o,i,k]*X[b,i,y+dy,x+dx]
// grid: B*32*16 blocks; block = (b, o, 4-row tile). 256 thr = 4 rows x 64 cols.
// Zero padding via per-thread 0/1 masks (i-independent, hoisted).
// ---------------------------------------------------------------------------
__global__ __launch_bounds__(256) void k_conv(const float* __restrict__ X,
                                              const float* __restrict__ wEff,
                                              const float* __restrict__ bias,
                                              float* __restrict__ out) {
    int blk = blockIdx.x;
    int b   = blk / 512;
    int rem = blk - b*512;
    int o   = rem >> 4;
    int rt  = rem & 15;

    __shared__ float lw[CCH*9];
    const float* wsrc = wEff + (size_t)((b*CCH + o)*CCH)*9;
    for (int r = threadIdx.x; r < CCH*9; r += 256) lw[r] = wsrc[r];
    __syncthreads();

    int x = threadIdx.x & 63;
    int y = rt*4 + (threadIdx.x >> 6);
    int xl = max(x-1, 0), xr = min(x+1, 63);
    int yu = max(y-1, 0), yd = min(y+1, 63);
    float mxl = (x > 0)  ? 1.f : 0.f;
    float mxr = (x < 63) ? 1.f : 0.f;
    float myu = (y > 0)  ? 1.f : 0.f;
    float myd = (y < 63) ? 1.f : 0.f;
    float m0 = myu*mxl, m1 = myu, m2 = myu*mxr;
    float m3 = mxl,               m5 = mxr;
    float m6 = myd*mxl, m7 = myd, m8 = myd*mxr;

    const float* plane = X + (size_t)b*CCH*NPIX;
    int ou = yu*64, o0 = y*64, od = yd*64;
    float acc = bias[o];
    #pragma unroll 4
    for (int i = 0; i < CCH; ++i) {
        const float* p   = plane + i*NPIX;
        const float* lwi = lw + i*9;
        float v0 = p[ou + xl] * m0;
        float v1 = p[ou + x ] * m1;
        float v2 = p[ou + xr] * m2;
        float v3 = p[o0 + xl] * m3;
        float v4 = p[o0 + x ];
        float v5 = p[o0 + xr] * m5;
        float v6 = p[od + xl] * m6;
        float v7 = p[od + x ] * m7;
        float v8 = p[od + xr] * m8;
        acc = fmaf(lwi[0], v0, acc);
        acc = fmaf(lwi[1], v1, acc);
        acc = fmaf(lwi[2], v2, acc);
        acc = fmaf(lwi[3], v3, acc);
        acc = fmaf(lwi[4], v4, acc);
        acc = fmaf(lwi[5], v5, acc);
        acc = fmaf(lwi[6], v6, acc);
        acc = fmaf(lwi[7], v7, acc);
        acc = fmaf(lwi[8], v8, acc);
    }
    out[(size_t)(b*CCH + o)*NPIX + y*64 + x] = acc;
}

// ---------------------------------------------------------------------------
// K4: per-channel BN stats over (B,H,W); emits fused scale/shift.
// grid: 32 blocks (one per channel), 256 threads, double accumulation.
// ---------------------------------------------------------------------------
__global__ __launch_bounds__(256) void k_stats(const float* __restrict__ conv_out,
                                               const float* __restrict__ gamma,
                                               const float* __restrict__ beta,
                                               float* __restrict__ ss) { // [0..31]=scale, [32..63]=shift
    int c = blockIdx.x;
    double s = 0.0, s2 = 0.0;
    for (int b = 0; b < BB; ++b) {
        const float4* p = (const float4*)(conv_out + (size_t)(b*CCH + c)*NPIX);
        for (int k = threadIdx.x; k < NPIX/4; k += 256) {
            float4 v = p[k];
            s  += (double)v.x + (double)v.y + (double)v.z + (double)v.w;
            s2 += (double)v.x*v.x + (double)v.y*v.y + (double)v.z*v.z + (double)v.w*v.w;
        }
    }
    #pragma unroll
    for (int off = 32; off > 0; off >>= 1) {
        s  += __shfl_down(s,  off, 64);
        s2 += __shfl_down(s2, off, 64);
    }
    __shared__ double rs[4], rs2[4];
    int lane = threadIdx.x & 63, wid = threadIdx.x >> 6;
    if (lane == 0) { rs[wid] = s; rs2[wid] = s2; }
    __syncthreads();
    if (threadIdx.x == 0) {
        double S  = rs[0] + rs[1] + rs[2] + rs[3];
        double S2 = rs2[0] + rs2[1] + rs2[2] + rs2[3];
        double n    = (double)(BB * NPIX);
        double mean = S / n;
        double var  = S2 / n - mean*mean;
        float invstd = (float)(1.0 / sqrt(var + 1e-5));
        float sc = gamma[c] * invstd;
        float sh = beta[c] - (float)mean * sc;
        ss[c]      = sc;
        ss[32 + c] = sh;
    }
}

// ---------------------------------------------------------------------------
// K5: BN + ReLU + 2x2 maxpool (LDS) + bilinear align_corners x2 upsample *2
//     + 0.2*f, fused. grid: B*32 blocks (b,c), 256 threads.
// ---------------------------------------------------------------------------
__global__ __launch_bounds__(256) void k_tail(const float* __restrict__ conv_out,
                                              const float* __restrict__ ss,
                                              const float* __restrict__ f,
                                              float* __restrict__ out) {
    int b = blockIdx.x >> 5;
    int c = blockIdx.x & 31;
    float sc = ss[c];
    float sh = ss[32 + c];
    const float* plane = conv_out + (size_t)(b*CCH + c)*NPIX;
    __shared__ float pool[32*32];
    int t = threadIdx.x;
    #pragma unroll
    for (int q = 0; q < 4; ++q) {
        int idx = t + q*256;                // pooled index 0..1023
        int py = idx >> 5, px = idx & 31;
        float2 a = *(const float2*)(plane + (2*py)*64   + 2*px);
        float2 d = *(const float2*)(plane + (2*py+1)*64 + 2*px);
        float v0 = fmaxf(fmaf(a.x, sc, sh), 0.f);
        float v1 = fmaxf(fmaf(a.y, sc, sh), 0.f);
        float v2 = fmaxf(fmaf(d.x, sc, sh), 0.f);
        float v3 = fmaxf(fmaf(d.y, sc, sh), 0.f);
        pool[idx] = fmaxf(fmaxf(v0, v1), fmaxf(v2, v3));
    }
    __syncthreads();
    const float r = 31.f / 63.f;            // (h-1)/(oh-1), align_corners
    const float* fp = f   + (size_t)(b*CCH + c)*NPIX;
    float*       op = out + (size_t)(b*CCH + c)*NPIX;
    #pragma unroll
    for (int q = 0; q < 16; ++q) {
        int idx = t + q*256;                // output pixel 0..4095
        int oy = idx >> 6, ox = idx & 63;
        float ysf = (float)oy * r;
        float xsf = (float)ox * r;
        int y0 = (int)ysf;                  // floor (non-negative)
        int x0 = (int)xsf;
        float wy = ysf - (float)y0;
        float wx = xsf - (float)x0;
        int y1 = min(y0 + 1, 31);
        int x1 = min(x0 + 1, 31);
        float p00 = pool[y0*32 + x0];
        float p01 = pool[y0*32 + x1];
        float p10 = pool[y1*32 + x0];
        float p11 = pool[y1*32 + x1];
        float top = p00 + (p01 - p00) * wx;
        float bot = p10 + (p11 - p10) * wx;
        float val = 2.f * (top + (bot - top) * wy);
        op[idx] = val + 0.2f * fp[idx];
    }
}

// ---------------------------------------------------------------------------
extern "C" void kernel_launch(void* const* d_in, const int* in_sizes, int n_in,
                              void* d_out, int out_size, void* d_ws, size_t ws_size,
                              hipStream_t stream) {
    const float* X   = (const float*)d_in[0];  // X_tnext      (2,32,64,64)
    const float* Xh  = (const float*)d_in[1];  // X_hat_tnext  (2,32,64,64)
    const float* f   = (const float*)d_in[2];  // f_tprev_t    (2,32,64,64)
    const float* wC  = (const float*)d_in[3];  // conv_w       (32,32,3,3)
    const float* bC  = (const float*)d_in[4];  // conv_b       (32,)
    const float* gam = (const float*)d_in[5];  // bn_gamma     (32,)
    const float* bet = (const float*)d_in[6];  // bn_beta      (32,)
    float* out = (float*)d_out;

    float* W     = (float*)d_ws;
    float* G     = W;              // 2048 floats
    float* wEff  = W + 2048;       // 18432 floats
    float* ss    = W + 20480;      // 64 floats (scale|shift)
    float* convo = W + 20544;      // 262144 floats

    hipLaunchKernelGGL(k_gram,  dim3(2048), dim3(256), 0, stream, X, Xh, G);
    hipLaunchKernelGGL(k_weff,  dim3(64),   dim3(256), 0, stream, wC, G, wEff);
    hipLaunchKernelGGL(k_conv,  dim3(1024), dim3(256), 0, stream, X, wEff, bC, convo);
    hipLaunchKernelGGL(k_stats, dim3(32),   dim3(256), 0, stream, convo, gam, bet, ss);
    hipLaunchKernelGGL(k_tail,  dim3(64),   dim3(256), 0, stream, convo, ss, f, out);
}